// Round 7
// baseline (254.487 us; speedup 1.0000x reference)
//
#include <hip/hip_runtime.h>
#include <cstdint>
#include <cstddef>

#define BB 96
#define SS 4
#define TT 16
#define KK 36
#define VDIM 1024
#define QDIM 512
#define HH 512
#define W1R 1536
#define NROWS 3264
#define MM (NROWS * KK)   // 117504

typedef __attribute__((ext_vector_type(8))) short short8;
typedef __attribute__((ext_vector_type(4))) float f32x4;
typedef __attribute__((ext_vector_type(4))) unsigned short ushort4v;

static __device__ __forceinline__ unsigned short f2bf(float f) {
    union { float f; unsigned u; } v; v.f = f;
    unsigned u = v.u;
    u += 0x7FFFu + ((u >> 16) & 1u);   // RNE
    return (unsigned short)(u >> 16);
}

__device__ __forceinline__ void gload_lds16(const void* g, void* l) {
    __builtin_amdgcn_global_load_lds(
        (const __attribute__((address_space(1))) unsigned int*)g,
        (__attribute__((address_space(3))) unsigned int*)l, 16, 0, 0);
}

#define SB() __builtin_amdgcn_sched_barrier(0)

// ---------------------------------------------------------------------------
// Kernel 0: w1 (fp32 [1536][512]) -> w1T bf16 [512][1536]. grid (6, 512).
// ---------------------------------------------------------------------------
__global__ __launch_bounds__(256) void prep_w1T(const float* __restrict__ w1,
                                                unsigned short* __restrict__ w1T) {
    int k = blockIdx.x * 256 + threadIdx.x;   // 0..1535
    int c = blockIdx.y;                       // 0..511
    w1T[(size_t)c * W1R + k] = f2bf(w1[(size_t)k * HH + c]);
}

// ---------------------------------------------------------------------------
// Kernel 1: per-(b,s) segment starts/lengths via LDS scan (one block)
// ---------------------------------------------------------------------------
__global__ __launch_bounds__(512) void starts_kernel(const int* __restrict__ tags,
                                                     int* __restrict__ starts,
                                                     int* __restrict__ lengths) {
    __shared__ int sl[BB * SS];
    int tid = threadIdx.x;
    int len = 0;
    if (tid < BB * SS) {
#pragma unroll
        for (int i = 0; i < TT; ++i) len += tags[tid * TT + i];
        sl[tid] = len;
    }
    __syncthreads();
    for (int off = 1; off < BB * SS; off <<= 1) {
        int v = 0;
        if (tid < BB * SS && tid >= off) v = sl[tid - off];
        __syncthreads();
        if (tid < BB * SS) sl[tid] += v;
        __syncthreads();
    }
    if (tid < BB * SS) { starts[tid] = sl[tid] - len; lengths[tid] = len; }
}

// ---------------------------------------------------------------------------
// Kernel 2: qproj via MFMA. Tile 64(M) x 128(N), K=512 (8 steps of 64).
// grid 51*4. 256 thr = 4 waves (2x2), wave tile 32x64, acc[2][4].
// ---------------------------------------------------------------------------
__global__ __launch_bounds__(256, 3) void qproj_mfma(const float* __restrict__ q,
                                                     const unsigned short* __restrict__ w1T,
                                                     const float* __restrict__ b1,
                                                     float* __restrict__ qp) {
    __shared__ __align__(16) unsigned short At[2][64 * 64];    // 16 KB
    __shared__ __align__(16) unsigned short Bt[2][128 * 64];   // 32 KB

    int tid = threadIdx.x, lane = tid & 63, wid = tid >> 6;
    int wm = wid >> 1, wn = wid & 1;
    int bx = blockIdx.x;
    int nb = bx & 3, mb = bx >> 2;
    int n0q = mb * 64, cb = nb * 128;
    int lr = lane & 15, lg = lane >> 4;

    const float* a_base = q + (size_t)(n0q + wid * 16 + (lane >> 4)) * QDIM + (lane & 15) * 4;
    const unsigned short* b_base = w1T + (size_t)(cb + wid * 32 + (lane >> 3)) * W1R + 1024
                                 + (((lane & 7) ^ (lane >> 3)) * 8);

    f32x4 acc[2][4];
#pragma unroll
    for (int mt = 0; mt < 2; ++mt)
#pragma unroll
        for (int nt = 0; nt < 4; ++nt) acc[mt][nt] = (f32x4){0.f, 0.f, 0.f, 0.f};

#define QP_CVT_WRITE(DST, AR)                                                  \
    _Pragma("unroll") for (int p = 0; p < 4; ++p) {                            \
        int r = wid * 16 + (lane >> 4) + p * 4;                                \
        int boff = r * 128 + ((((lane & 15) * 8)) ^ ((r & 7) << 4));           \
        unsigned short t4[4] = {f2bf(AR[p].x), f2bf(AR[p].y),                  \
                                f2bf(AR[p].z), f2bf(AR[p].w)};                 \
        *(ushort4v*)((char*)(DST) + boff) = *(const ushort4v*)t4;              \
    }

#define QP_COMPUTE(AC, BC)                                                     \
    _Pragma("unroll") for (int kk = 0; kk < 2; ++kk) {                         \
        short8 af[2], bf[4];                                                   \
        _Pragma("unroll") for (int mt = 0; mt < 2; ++mt) {                     \
            int R = wm * 32 + mt * 16 + lr;                                    \
            int off = R * 128 + ((kk * 64 + lg * 16) ^ ((R & 7) << 4));        \
            af[mt] = *(const short8*)((const char*)(AC) + off);                \
        }                                                                      \
        _Pragma("unroll") for (int nt = 0; nt < 4; ++nt) {                     \
            int R = wn * 64 + nt * 16 + lr;                                    \
            int off = R * 128 + ((kk * 64 + lg * 16) ^ ((R & 7) << 4));        \
            bf[nt] = *(const short8*)((const char*)(BC) + off);                \
        }                                                                      \
        __builtin_amdgcn_s_setprio(1);                                         \
        _Pragma("unroll") for (int mt = 0; mt < 2; ++mt)                       \
            _Pragma("unroll") for (int nt = 0; nt < 4; ++nt)                   \
                acc[mt][nt] = __builtin_amdgcn_mfma_f32_16x16x32_bf16(         \
                    af[mt], bf[nt], acc[mt][nt], 0, 0, 0);                     \
        __builtin_amdgcn_s_setprio(0);                                         \
    }

    // prologue
    {
        float4 ar[4];
#pragma unroll
        for (int p = 0; p < 4; ++p) ar[p] = *(const float4*)(a_base + (size_t)p * 4 * QDIM);
#pragma unroll
        for (int o = 0; o < 4; ++o)
            gload_lds16(b_base + (size_t)o * 8 * W1R, &Bt[0][(wid * 32 + o * 8) * 64]);
        SB();
        QP_CVT_WRITE(&At[0][0], ar)
    }
#pragma unroll 1
    for (int t = 0; t < 7; ++t) {
        int k0 = (t + 1) * 64;
        const unsigned short* Ac = &At[t & 1][0];
        const unsigned short* Bc = &Bt[t & 1][0];
        unsigned short* An = &At[(t + 1) & 1][0];
        unsigned short* Bn = &Bt[(t + 1) & 1][0];
        float4 ar[4];
#pragma unroll
        for (int p = 0; p < 4; ++p)
            ar[p] = *(const float4*)(a_base + (size_t)p * 4 * QDIM + k0);
#pragma unroll
        for (int o = 0; o < 4; ++o)
            gload_lds16(b_base + (size_t)o * 8 * W1R + k0, &Bn[(wid * 32 + o * 8) * 64]);
        SB();
        asm volatile("s_waitcnt vmcnt(8)" ::: "memory");
        asm volatile("s_waitcnt lgkmcnt(0)" ::: "memory");
        __builtin_amdgcn_s_barrier();
        SB();
        QP_COMPUTE(Ac, Bc)
        SB();
        QP_CVT_WRITE(An, ar)
    }
    SB();
    asm volatile("s_waitcnt vmcnt(0)" ::: "memory");
    asm volatile("s_waitcnt lgkmcnt(0)" ::: "memory");
    __builtin_amdgcn_s_barrier();
    SB();
    QP_COMPUTE(&At[1][0], &Bt[1][0])
#undef QP_COMPUTE
#undef QP_CVT_WRITE

    // store qp + b1
#pragma unroll
    for (int nt = 0; nt < 4; ++nt) {
        int c = cb + wn * 64 + nt * 16 + lr;
        float b1v = b1[c];
#pragma unroll
        for (int mt = 0; mt < 2; ++mt)
#pragma unroll
            for (int r = 0; r < 4; ++r) {
                int row = wm * 32 + mt * 16 + lg * 4 + r;
                qp[(size_t)(n0q + row) * HH + c] = acc[mt][nt][r] + b1v;
            }
    }
}

// ---------------------------------------------------------------------------
// Kernel 3: main GEMM. Tile 256(M) x 128(N), BK=64, 16 K-steps.
// grid 1836 (459 m-panels x 4 nb), bijective XCD chunking (q=229,r=4).
// 512 thr = 8 waves (4M x 2N), wave tile 64x64, acc[4][4].
// A: single-buffered LDS 32 KB (reg->bf16->swizzled ds_write).
// B: double-buffered global_load_lds 2x16 KB; DMA issued AFTER barrier1
// (race-free), counted vmcnt(8) (never 0 in loop). LDS 64 KB -> 2 blk/CU.
// ---------------------------------------------------------------------------
__global__ __launch_bounds__(512, 4) void main_gemm(const float* __restrict__ v,
                                                    const unsigned short* __restrict__ w1T,
                                                    const float* __restrict__ qp,
                                                    const float* __restrict__ w2,
                                                    float* __restrict__ logits4) {
    __shared__ __align__(16) unsigned short At[256 * 64];      // 32 KB (single buf)
    __shared__ __align__(16) unsigned short Bt[2][128 * 64];   // 32 KB

    int tid = threadIdx.x, lane = tid & 63, wid = tid >> 6;   // wid 0..7
    int wm = wid >> 1, wn = wid & 1;
    int bx = blockIdx.x;
    int xcd = bx & 7;
    int base = (xcd < 4) ? xcd * 230 : 920 + (xcd - 4) * 229;
    int orig = base + (bx >> 3);                // bijective XCD chunking, 1836
    int nb = orig & 3, mb = orig >> 2;
    int m0 = mb * 256, cb = nb * 128;
    int lr = lane & 15, lg = lane >> 4;

    const float* a_base = v + (size_t)(m0 + wid * 32 + (lane >> 4)) * VDIM + (lane & 15) * 4;
    const unsigned short* b_base = w1T + (size_t)(cb + wid * 16 + (lane >> 3)) * W1R
                                 + (((lane & 7) ^ (lane >> 3)) * 8);

    f32x4 acc[4][4];
#pragma unroll
    for (int mt = 0; mt < 4; ++mt)
#pragma unroll
        for (int nt = 0; nt < 4; ++nt) acc[mt][nt] = (f32x4){0.f, 0.f, 0.f, 0.f};

#define MG_CVT_WRITE(AR)                                                       \
    _Pragma("unroll") for (int p = 0; p < 8; ++p) {                            \
        int r = wid * 32 + (lane >> 4) + p * 4;                                \
        int boff = r * 128 + ((((lane & 15) * 8)) ^ ((r & 7) << 4));           \
        unsigned short t4[4] = {f2bf(AR[p].x), f2bf(AR[p].y),                  \
                                f2bf(AR[p].z), f2bf(AR[p].w)};                 \
        *(ushort4v*)((char*)&At[0] + boff) = *(const ushort4v*)t4;             \
    }

#define MG_READ_A(AF, KKC)                                                     \
    _Pragma("unroll") for (int mt = 0; mt < 4; ++mt) {                         \
        int R = wm * 64 + mt * 16 + lr;                                        \
        int off = R * 128 + (((KKC) * 64 + lg * 16) ^ ((R & 7) << 4));         \
        AF[mt] = *(const short8*)((const char*)&At[0] + off);                  \
    }

#define MG_READ_B(BF, BC, KKC)                                                 \
    _Pragma("unroll") for (int nt = 0; nt < 4; ++nt) {                         \
        int R = wn * 64 + nt * 16 + lr;                                        \
        int off = R * 128 + (((KKC) * 64 + lg * 16) ^ ((R & 7) << 4));         \
        BF[nt] = *(const short8*)((const char*)(BC) + off);                    \
    }

#define MG_MFMA(AF, BF)                                                        \
    __builtin_amdgcn_s_setprio(1);                                             \
    _Pragma("unroll") for (int mt = 0; mt < 4; ++mt)                           \
        _Pragma("unroll") for (int nt = 0; nt < 4; ++nt)                       \
            acc[mt][nt] = __builtin_amdgcn_mfma_f32_16x16x32_bf16(             \
                AF[mt], BF[nt], acc[mt][nt], 0, 0, 0);                         \
    __builtin_amdgcn_s_setprio(0);

    // ---- prologue: B(0) DMA -> Bt[0]; A(0) -> regs -> cvt -> At ----
    {
#pragma unroll
        for (int o = 0; o < 2; ++o)
            gload_lds16(b_base + (size_t)o * 8 * W1R, &Bt[0][(wid * 16 + o * 8) * 64]);
        float4 ar[8];
#pragma unroll
        for (int p = 0; p < 8; ++p) ar[p] = *(const float4*)(a_base + (size_t)p * 4 * VDIM);
        SB();
        MG_CVT_WRITE(ar)
    }

#pragma unroll 1
    for (int t = 0; t < 16; ++t) {
        int kA = (t < 15) ? (t + 1) * 64 : 960;     // last iter: harmless dummy
        const unsigned short* Bc = &Bt[t & 1][0];
        unsigned short* Bn = &Bt[(t + 1) & 1][0];
        // issue A(t+1) -> regs  [8 vmem, newest]
        float4 ar[8];
#pragma unroll
        for (int p = 0; p < 8; ++p)
            ar[p] = *(const float4*)(a_base + (size_t)p * 4 * VDIM + kA);
        SB();
        asm volatile("s_waitcnt vmcnt(8)" ::: "memory");    // B(t) landed
        asm volatile("s_waitcnt lgkmcnt(0)" ::: "memory");  // my At writes done
        __builtin_amdgcn_s_barrier();                       // At(t)+B(t) visible; Bt[nxt] free
        SB();
        // issue B(t+1) DMA (race-free: all waves past compute(t-1))
#pragma unroll
        for (int o = 0; o < 2; ++o)
            gload_lds16(b_base + (size_t)o * 8 * W1R + kA, Bn + (wid * 16 + o * 8) * 64);
        SB();
        // kk0
        {
            short8 af0[4], bf0[4];
            MG_READ_A(af0, 0)
            MG_READ_B(bf0, Bc, 0)
            MG_MFMA(af0, bf0)
        }
        // kk1 reads, then barrier before At overwrite
        short8 af1[4], bf1[4];
        MG_READ_A(af1, 1)
        MG_READ_B(bf1, Bc, 1)
        SB();
        asm volatile("s_waitcnt lgkmcnt(0)" ::: "memory");  // my At/Bt reads done
        __builtin_amdgcn_s_barrier();                       // all waves done reading At
        SB();
        MG_MFMA(af1, bf1)
        if (t < 15) { MG_CVT_WRITE(ar) }                    // At <- A(t+1)
    }
#undef MG_MFMA
#undef MG_READ_A
#undef MG_READ_B
#undef MG_CVT_WRITE

    // ---- epilogue: relu(acc + qp) . w2 -> partial logits for cols [cb,cb+128)
    __syncthreads();   // drains dummy loads/DMA, frees At for reuse
    float* qs = (float*)&At[0];         // 9 x 128 slab of qp (4.5 KB)
    float* fl = qs + 9 * 128;           // 2 x 256 reduction scratch (2 KB)
    int n0 = m0 / KK;
    for (int i = tid; i < 9 * 128; i += 512) {
        int nn = n0 + (i >> 7);
        if (nn >= NROWS) nn = NROWS - 1;
        qs[i] = qp[(size_t)nn * HH + cb + (i & 127)];
    }
    __syncthreads();

    float part[4][4] = {{0.f}};
#pragma unroll
    for (int nt = 0; nt < 4; ++nt) {
        int c = wn * 64 + nt * 16 + lr;
        float w2v = w2[cb + c];
#pragma unroll
        for (int mt = 0; mt < 4; ++mt)
#pragma unroll
            for (int r = 0; r < 4; ++r) {
                int row = wm * 64 + mt * 16 + lg * 4 + r;
                int ni = (m0 + row) / KK - n0;
                float pre = acc[mt][nt][r] + qs[ni * 128 + c];
                part[mt][r] += fmaxf(pre, 0.f) * w2v;
            }
    }
#pragma unroll
    for (int mt = 0; mt < 4; ++mt)
#pragma unroll
        for (int r = 0; r < 4; ++r) {
            float s = part[mt][r];
            s += __shfl_xor(s, 1, 64);
            s += __shfl_xor(s, 2, 64);
            s += __shfl_xor(s, 4, 64);
            s += __shfl_xor(s, 8, 64);
            if (lr == 0) fl[wn * 256 + wm * 64 + mt * 16 + lg * 4 + r] = s;
        }
    __syncthreads();
    if (tid < 256)
        logits4[(size_t)nb * MM + m0 + tid] = fl[tid] + fl[256 + tid];
}

// ---------------------------------------------------------------------------
// Kernel 4: masked softmax. One wave per (b,s,t); sums 4 logit partials.
// ---------------------------------------------------------------------------
__global__ __launch_bounds__(256) void softmax_kernel(const float* __restrict__ logits4,
                                                      const float* __restrict__ box_mask,
                                                      const int* __restrict__ starts,
                                                      const int* __restrict__ lengths,
                                                      float* __restrict__ out) {
    int lane = threadIdx.x & 63;
    int g = blockIdx.x * 4 + (threadIdx.x >> 6);   // 0 .. B*S*T-1
    int t   = g & (TT - 1);
    int row = g >> 4;
    int b   = row >> 2;

    int length = lengths[row];
    int start  = starts[row];

    int k = lane;
    bool kv = k < KK;
    float mval = kv ? box_mask[b * KK + k] : 0.f;
    bool act = kv && (mval != 0.f);

    float l = 0.f;
    if (act && t < length) {
        size_t idx = (size_t)(start + t) * KK + k;
        l = logits4[idx] + logits4[MM + idx] + logits4[2 * (size_t)MM + idx]
          + logits4[3 * (size_t)MM + idx];
    }

    float lm = act ? l : -1e30f;
#pragma unroll
    for (int off = 32; off >= 1; off >>= 1) lm = fmaxf(lm, __shfl_xor(lm, off, 64));

    float e = act ? expf(l - lm) : 0.f;
    float se = e;
#pragma unroll
    for (int off = 32; off >= 1; off >>= 1) se += __shfl_xor(se, off, 64);

    if (kv) out[(size_t)g * KK + k] = e / se;
}

// ---------------------------------------------------------------------------
extern "C" void kernel_launch(void* const* d_in, const int* in_sizes, int n_in,
                              void* d_out, int out_size, void* d_ws, size_t ws_size,
                              hipStream_t stream) {
    const float* v        = (const float*)d_in[0];
    const float* q        = (const float*)d_in[1];
    const float* box_mask = (const float*)d_in[2];
    const int*   tags     = (const int*)d_in[3];
    const float* w1       = (const float*)d_in[4];
    const float* b1       = (const float*)d_in[5];
    const float* w2       = (const float*)d_in[6];

    char* ws = (char*)d_ws;
    unsigned short* w1T   = (unsigned short*)ws;                 // 1,572,864 B
    float* qp      = (float*)(ws + 1572864);                     // 6,684,672 B
    float* logits4 = (float*)(ws + 1572864 + 6684672);           // 1,880,064 B
    int*   starts  = (int*)(ws + 1572864 + 6684672 + 1880064);
    int*   lengths = (int*)(ws + 1572864 + 6684672 + 1880064 + 1536);
    float* out     = (float*)d_out;

    hipLaunchKernelGGL(prep_w1T, dim3(6, 512), dim3(256), 0, stream, w1, w1T);
    hipLaunchKernelGGL(starts_kernel, dim3(1), dim3(512), 0, stream, tags, starts, lengths);
    hipLaunchKernelGGL(qproj_mfma, dim3((NROWS / 64) * 4), dim3(256), 0, stream,
                       q, w1T, b1, qp);
    hipLaunchKernelGGL(main_gemm, dim3((MM / 256) * 4), dim3(512), 0, stream,
                       v, w1T, qp, w2, logits4);
    hipLaunchKernelGGL(softmax_kernel, dim3((BB * SS * TT) / 4), dim3(256), 0, stream,
                       logits4, box_mask, starts, lengths, out);
}

// Round 8
// 235.884 us; speedup vs baseline: 1.0789x; 1.0789x over previous
//
#include <hip/hip_runtime.h>
#include <cstdint>
#include <cstddef>

#define BB 96
#define SS 4
#define TT 16
#define KK 36
#define VDIM 1024
#define QDIM 512
#define HH 512
#define W1R 1536
#define NROWS 3264
#define MM (NROWS * KK)   // 117504

typedef __attribute__((ext_vector_type(8))) short short8;
typedef __attribute__((ext_vector_type(4))) float f32x4;
typedef __attribute__((ext_vector_type(4))) unsigned short ushort4v;

static __device__ __forceinline__ unsigned short f2bf(float f) {
    union { float f; unsigned u; } v; v.f = f;
    unsigned u = v.u;
    u += 0x7FFFu + ((u >> 16) & 1u);   // RNE
    return (unsigned short)(u >> 16);
}

__device__ __forceinline__ void gload_lds16(const void* g, void* l) {
    __builtin_amdgcn_global_load_lds(
        (const __attribute__((address_space(1))) unsigned int*)g,
        (__attribute__((address_space(3))) unsigned int*)l, 16, 0, 0);
}

#define SB() __builtin_amdgcn_sched_barrier(0)

// ---------------------------------------------------------------------------
// Kernel 0: w1 (fp32 [1536][512]) -> w1T bf16 [512][1536]. grid (6, 512).
// ---------------------------------------------------------------------------
__global__ __launch_bounds__(256) void prep_w1T(const float* __restrict__ w1,
                                                unsigned short* __restrict__ w1T) {
    int k = blockIdx.x * 256 + threadIdx.x;   // 0..1535
    int c = blockIdx.y;                       // 0..511
    w1T[(size_t)c * W1R + k] = f2bf(w1[(size_t)k * HH + c]);
}

// ---------------------------------------------------------------------------
// Kernel 1: per-(b,s) segment starts/lengths via LDS scan (one block)
// ---------------------------------------------------------------------------
__global__ __launch_bounds__(512) void starts_kernel(const int* __restrict__ tags,
                                                     int* __restrict__ starts,
                                                     int* __restrict__ lengths) {
    __shared__ int sl[BB * SS];
    int tid = threadIdx.x;
    int len = 0;
    if (tid < BB * SS) {
#pragma unroll
        for (int i = 0; i < TT; ++i) len += tags[tid * TT + i];
        sl[tid] = len;
    }
    __syncthreads();
    for (int off = 1; off < BB * SS; off <<= 1) {
        int v = 0;
        if (tid < BB * SS && tid >= off) v = sl[tid - off];
        __syncthreads();
        if (tid < BB * SS) sl[tid] += v;
        __syncthreads();
    }
    if (tid < BB * SS) { starts[tid] = sl[tid] - len; lengths[tid] = len; }
}

// ---------------------------------------------------------------------------
// Kernel 2: qproj via MFMA. Tile 64(M) x 128(N), K=512 (8 steps of 64).
// grid 51*4. 256 thr = 4 waves (2x2), wave tile 32x64, acc[2][4].
// ---------------------------------------------------------------------------
__global__ __launch_bounds__(256, 3) void qproj_mfma(const float* __restrict__ q,
                                                     const unsigned short* __restrict__ w1T,
                                                     const float* __restrict__ b1,
                                                     float* __restrict__ qp) {
    __shared__ __align__(16) unsigned short At[2][64 * 64];    // 16 KB
    __shared__ __align__(16) unsigned short Bt[2][128 * 64];   // 32 KB

    int tid = threadIdx.x, lane = tid & 63, wid = tid >> 6;
    int wm = wid >> 1, wn = wid & 1;
    int bx = blockIdx.x;
    int nb = bx & 3, mb = bx >> 2;
    int n0q = mb * 64, cb = nb * 128;
    int lr = lane & 15, lg = lane >> 4;

    const float* a_base = q + (size_t)(n0q + wid * 16 + (lane >> 4)) * QDIM + (lane & 15) * 4;
    const unsigned short* b_base = w1T + (size_t)(cb + wid * 32 + (lane >> 3)) * W1R + 1024
                                 + (((lane & 7) ^ (lane >> 3)) * 8);

    f32x4 acc[2][4];
#pragma unroll
    for (int mt = 0; mt < 2; ++mt)
#pragma unroll
        for (int nt = 0; nt < 4; ++nt) acc[mt][nt] = (f32x4){0.f, 0.f, 0.f, 0.f};

#define QP_CVT_WRITE(DST, AR)                                                  \
    _Pragma("unroll") for (int p = 0; p < 4; ++p) {                            \
        int r = wid * 16 + (lane >> 4) + p * 4;                                \
        int boff = r * 128 + ((((lane & 15) * 8)) ^ ((r & 7) << 4));           \
        unsigned short t4[4] = {f2bf(AR[p].x), f2bf(AR[p].y),                  \
                                f2bf(AR[p].z), f2bf(AR[p].w)};                 \
        *(ushort4v*)((char*)(DST) + boff) = *(const ushort4v*)t4;              \
    }

#define QP_COMPUTE(AC, BC)                                                     \
    _Pragma("unroll") for (int kk = 0; kk < 2; ++kk) {                         \
        short8 af[2], bf[4];                                                   \
        _Pragma("unroll") for (int mt = 0; mt < 2; ++mt) {                     \
            int R = wm * 32 + mt * 16 + lr;                                    \
            int off = R * 128 + ((kk * 64 + lg * 16) ^ ((R & 7) << 4));        \
            af[mt] = *(const short8*)((const char*)(AC) + off);                \
        }                                                                      \
        _Pragma("unroll") for (int nt = 0; nt < 4; ++nt) {                     \
            int R = wn * 64 + nt * 16 + lr;                                    \
            int off = R * 128 + ((kk * 64 + lg * 16) ^ ((R & 7) << 4));        \
            bf[nt] = *(const short8*)((const char*)(BC) + off);                \
        }                                                                      \
        __builtin_amdgcn_s_setprio(1);                                         \
        _Pragma("unroll") for (int mt = 0; mt < 2; ++mt)                       \
            _Pragma("unroll") for (int nt = 0; nt < 4; ++nt)                   \
                acc[mt][nt] = __builtin_amdgcn_mfma_f32_16x16x32_bf16(         \
                    af[mt], bf[nt], acc[mt][nt], 0, 0, 0);                     \
        __builtin_amdgcn_s_setprio(0);                                         \
    }

    // prologue
    {
        float4 ar[4];
#pragma unroll
        for (int p = 0; p < 4; ++p) ar[p] = *(const float4*)(a_base + (size_t)p * 4 * QDIM);
#pragma unroll
        for (int o = 0; o < 4; ++o)
            gload_lds16(b_base + (size_t)o * 8 * W1R, &Bt[0][(wid * 32 + o * 8) * 64]);
        SB();
        QP_CVT_WRITE(&At[0][0], ar)
    }
#pragma unroll 1
    for (int t = 0; t < 7; ++t) {
        int k0 = (t + 1) * 64;
        const unsigned short* Ac = &At[t & 1][0];
        const unsigned short* Bc = &Bt[t & 1][0];
        unsigned short* An = &At[(t + 1) & 1][0];
        unsigned short* Bn = &Bt[(t + 1) & 1][0];
        float4 ar[4];
#pragma unroll
        for (int p = 0; p < 4; ++p)
            ar[p] = *(const float4*)(a_base + (size_t)p * 4 * QDIM + k0);
#pragma unroll
        for (int o = 0; o < 4; ++o)
            gload_lds16(b_base + (size_t)o * 8 * W1R + k0, &Bn[(wid * 32 + o * 8) * 64]);
        SB();
        asm volatile("s_waitcnt vmcnt(8)" ::: "memory");
        asm volatile("s_waitcnt lgkmcnt(0)" ::: "memory");
        __builtin_amdgcn_s_barrier();
        SB();
        QP_COMPUTE(Ac, Bc)
        SB();
        QP_CVT_WRITE(An, ar)
    }
    SB();
    asm volatile("s_waitcnt vmcnt(0)" ::: "memory");
    asm volatile("s_waitcnt lgkmcnt(0)" ::: "memory");
    __builtin_amdgcn_s_barrier();
    SB();
    QP_COMPUTE(&At[1][0], &Bt[1][0])
#undef QP_COMPUTE
#undef QP_CVT_WRITE

    // store qp + b1
#pragma unroll
    for (int nt = 0; nt < 4; ++nt) {
        int c = cb + wn * 64 + nt * 16 + lr;
        float b1v = b1[c];
#pragma unroll
        for (int mt = 0; mt < 2; ++mt)
#pragma unroll
            for (int r = 0; r < 4; ++r) {
                int row = wm * 32 + mt * 16 + lg * 4 + r;
                qp[(size_t)(n0q + row) * HH + c] = acc[mt][nt][r] + b1v;
            }
    }
}

// ---------------------------------------------------------------------------
// Kernel 3: main GEMM. Tile 128(M) x 128(N), BK=64, 16 K-steps.
// grid 3672 = 8 XCD-chunks of 459 (bijective).
// 256 thr = 4 waves (2x2), wave tile 64x64, acc[4][4].
// A: single-buffered LDS 16 KB. B: double-buffered global_load_lds 2x16 KB,
// DMA issued AFTER barrier1 (race-free), counted vmcnt(8) (never 0 in loop).
// kk-split: af/bf reads of kk1 overlap MFMA of kk0 (no LDS-only phase).
// LDS = 48 KB -> 3 blocks/CU.
// ---------------------------------------------------------------------------
__global__ __launch_bounds__(256, 3) void main_gemm(const float* __restrict__ v,
                                                    const unsigned short* __restrict__ w1T,
                                                    const float* __restrict__ qp,
                                                    const float* __restrict__ w2,
                                                    float* __restrict__ logits4) {
    __shared__ __align__(16) unsigned short At[128 * 64];      // 16 KB (single buf)
    __shared__ __align__(16) unsigned short Bt[2][128 * 64];   // 32 KB

    int tid = threadIdx.x, lane = tid & 63, wid = tid >> 6;
    int wm = wid >> 1, wn = wid & 1;
    int bx = blockIdx.x;
    int orig = (bx & 7) * 459 + (bx >> 3);      // bijective XCD chunking
    int nb = orig & 3, mb = orig >> 2;
    int m0 = mb * 128, cb = nb * 128;
    int lr = lane & 15, lg = lane >> 4;

    const float* a_base = v + (size_t)(m0 + wid * 32 + (lane >> 4)) * VDIM + (lane & 15) * 4;
    const unsigned short* b_base = w1T + (size_t)(cb + wid * 32 + (lane >> 3)) * W1R
                                 + (((lane & 7) ^ (lane >> 3)) * 8);

    f32x4 acc[4][4];
#pragma unroll
    for (int mt = 0; mt < 4; ++mt)
#pragma unroll
        for (int nt = 0; nt < 4; ++nt) acc[mt][nt] = (f32x4){0.f, 0.f, 0.f, 0.f};

#define MG_CVT_WRITE(AR)                                                       \
    _Pragma("unroll") for (int p = 0; p < 8; ++p) {                            \
        int r = wid * 32 + (lane >> 4) + p * 4;                                \
        int boff = r * 128 + ((((lane & 15) * 8)) ^ ((r & 7) << 4));           \
        unsigned short t4[4] = {f2bf(AR[p].x), f2bf(AR[p].y),                  \
                                f2bf(AR[p].z), f2bf(AR[p].w)};                 \
        *(ushort4v*)((char*)&At[0] + boff) = *(const ushort4v*)t4;             \
    }

#define MG_READ_A(AF, KKC)                                                     \
    _Pragma("unroll") for (int mt = 0; mt < 4; ++mt) {                         \
        int R = wm * 64 + mt * 16 + lr;                                        \
        int off = R * 128 + (((KKC) * 64 + lg * 16) ^ ((R & 7) << 4));         \
        AF[mt] = *(const short8*)((const char*)&At[0] + off);                  \
    }

#define MG_READ_B(BF, BC, KKC)                                                 \
    _Pragma("unroll") for (int nt = 0; nt < 4; ++nt) {                         \
        int R = wn * 64 + nt * 16 + lr;                                        \
        int off = R * 128 + (((KKC) * 64 + lg * 16) ^ ((R & 7) << 4));         \
        BF[nt] = *(const short8*)((const char*)(BC) + off);                    \
    }

#define MG_MFMA(AF, BF)                                                        \
    __builtin_amdgcn_s_setprio(1);                                             \
    _Pragma("unroll") for (int mt = 0; mt < 4; ++mt)                           \
        _Pragma("unroll") for (int nt = 0; nt < 4; ++nt)                       \
            acc[mt][nt] = __builtin_amdgcn_mfma_f32_16x16x32_bf16(             \
                AF[mt], BF[nt], acc[mt][nt], 0, 0, 0);                         \
    __builtin_amdgcn_s_setprio(0);

    // ---- prologue: B(0) DMA -> Bt[0]; A(0) -> regs -> cvt -> At ----
    {
#pragma unroll
        for (int o = 0; o < 4; ++o)
            gload_lds16(b_base + (size_t)o * 8 * W1R, &Bt[0][(wid * 32 + o * 8) * 64]);
        float4 ar[8];
#pragma unroll
        for (int p = 0; p < 8; ++p) ar[p] = *(const float4*)(a_base + (size_t)p * 4 * VDIM);
        SB();
        MG_CVT_WRITE(ar)
    }

#pragma unroll 1
    for (int t = 0; t < 16; ++t) {
        int kA = (t < 15) ? (t + 1) * 64 : 960;     // last iter: harmless dummy
        const unsigned short* Bc = &Bt[t & 1][0];
        unsigned short* Bn = &Bt[(t + 1) & 1][0];
        // issue A(t+1) -> regs  [8 vmem, newest]
        float4 ar[8];
#pragma unroll
        for (int p = 0; p < 8; ++p)
            ar[p] = *(const float4*)(a_base + (size_t)p * 4 * VDIM + kA);
        SB();
        asm volatile("s_waitcnt vmcnt(8)" ::: "memory");    // B(t) landed (8 newer A in flight)
        asm volatile("s_waitcnt lgkmcnt(0)" ::: "memory");  // my At writes done
        __builtin_amdgcn_s_barrier();                       // At(t)+B(t) visible; Bt[nxt] free
        SB();
        // issue B(t+1) DMA AFTER barrier1: race-free (all waves past their bf reads)
        if (t < 15) {
#pragma unroll
            for (int o = 0; o < 4; ++o)
                gload_lds16(b_base + (size_t)o * 8 * W1R + kA, Bn + (wid * 32 + o * 8) * 64);
        }
        SB();
        // kk0 reads+MFMA; kk1 reads free to overlap kk0 MFMA (no SB between)
        {
            short8 af0[4], bf0[4];
            MG_READ_A(af0, 0)
            MG_READ_B(bf0, Bc, 0)
            MG_MFMA(af0, bf0)
        }
        {
            short8 af1[4], bf1[4];
            MG_READ_A(af1, 1)
            MG_READ_B(bf1, Bc, 1)
            MG_MFMA(af1, bf1)
        }
        SB();
        asm volatile("s_waitcnt lgkmcnt(0)" ::: "memory");  // my At/Bt reads done
        __builtin_amdgcn_s_barrier();                       // all waves done reading At
        SB();
        if (t < 15) { MG_CVT_WRITE(ar) }                    // At <- A(t+1)
    }
#undef MG_MFMA
#undef MG_READ_A
#undef MG_READ_B
#undef MG_CVT_WRITE

    // ---- epilogue: relu(acc + qp) . w2 -> partial logits for cols [cb,cb+128)
    __syncthreads();   // drains dummy loads, frees At for reuse
    float* qs = (float*)&At[0];         // 5 x 128 slab of qp
    float* fl = qs + 5 * 128;           // 2 x 128 reduction scratch
    int n0 = m0 / KK;
    for (int i = tid; i < 5 * 128; i += 256) {
        int nn = n0 + (i >> 7);
        if (nn >= NROWS) nn = NROWS - 1;
        qs[i] = qp[(size_t)nn * HH + cb + (i & 127)];
    }
    __syncthreads();

    float part[4][4] = {{0.f}};
#pragma unroll
    for (int nt = 0; nt < 4; ++nt) {
        int c = wn * 64 + nt * 16 + lr;
        float w2v = w2[cb + c];
#pragma unroll
        for (int mt = 0; mt < 4; ++mt)
#pragma unroll
            for (int r = 0; r < 4; ++r) {
                int row = wm * 64 + mt * 16 + lg * 4 + r;
                int ni = (m0 + row) / KK - n0;
                float pre = acc[mt][nt][r] + qs[ni * 128 + c];
                part[mt][r] += fmaxf(pre, 0.f) * w2v;
            }
    }
#pragma unroll
    for (int mt = 0; mt < 4; ++mt)
#pragma unroll
        for (int r = 0; r < 4; ++r) {
            float s = part[mt][r];
            s += __shfl_xor(s, 1, 64);
            s += __shfl_xor(s, 2, 64);
            s += __shfl_xor(s, 4, 64);
            s += __shfl_xor(s, 8, 64);
            if (lr == 0) fl[wn * 128 + wm * 64 + mt * 16 + lg * 4 + r] = s;
        }
    __syncthreads();
    if (tid < 128)
        logits4[(size_t)nb * MM + m0 + tid] = fl[tid] + fl[128 + tid];
}

// ---------------------------------------------------------------------------
// Kernel 4: masked softmax. One wave per (b,s,t); sums 4 logit partials.
// ---------------------------------------------------------------------------
__global__ __launch_bounds__(256) void softmax_kernel(const float* __restrict__ logits4,
                                                      const float* __restrict__ box_mask,
                                                      const int* __restrict__ starts,
                                                      const int* __restrict__ lengths,
                                                      float* __restrict__ out) {
    int lane = threadIdx.x & 63;
    int g = blockIdx.x * 4 + (threadIdx.x >> 6);   // 0 .. B*S*T-1
    int t   = g & (TT - 1);
    int row = g >> 4;
    int b   = row >> 2;

    int length = lengths[row];
    int start  = starts[row];

    int k = lane;
    bool kv = k < KK;
    float mval = kv ? box_mask[b * KK + k] : 0.f;
    bool act = kv && (mval != 0.f);

    float l = 0.f;
    if (act && t < length) {
        size_t idx = (size_t)(start + t) * KK + k;
        l = logits4[idx] + logits4[MM + idx] + logits4[2 * (size_t)MM + idx]
          + logits4[3 * (size_t)MM + idx];
    }

    float lm = act ? l : -1e30f;
#pragma unroll
    for (int off = 32; off >= 1; off >>= 1) lm = fmaxf(lm, __shfl_xor(lm, off, 64));

    float e = act ? expf(l - lm) : 0.f;
    float se = e;
#pragma unroll
    for (int off = 32; off >= 1; off >>= 1) se += __shfl_xor(se, off, 64);

    if (kv) out[(size_t)g * KK + k] = e / se;
}

// ---------------------------------------------------------------------------
extern "C" void kernel_launch(void* const* d_in, const int* in_sizes, int n_in,
                              void* d_out, int out_size, void* d_ws, size_t ws_size,
                              hipStream_t stream) {
    const float* v        = (const float*)d_in[0];
    const float* q        = (const float*)d_in[1];
    const float* box_mask = (const float*)d_in[2];
    const int*   tags     = (const int*)d_in[3];
    const float* w1       = (const float*)d_in[4];
    const float* b1       = (const float*)d_in[5];
    const float* w2       = (const float*)d_in[6];

    char* ws = (char*)d_ws;
    unsigned short* w1T   = (unsigned short*)ws;                 // 1,572,864 B
    float* qp      = (float*)(ws + 1572864);                     // 6,684,672 B
    float* logits4 = (float*)(ws + 1572864 + 6684672);           // 1,880,064 B
    int*   starts  = (int*)(ws + 1572864 + 6684672 + 1880064);
    int*   lengths = (int*)(ws + 1572864 + 6684672 + 1880064 + 1536);
    float* out     = (float*)d_out;

    hipLaunchKernelGGL(prep_w1T, dim3(6, 512), dim3(256), 0, stream, w1, w1T);
    hipLaunchKernelGGL(starts_kernel, dim3(1), dim3(512), 0, stream, tags, starts, lengths);
    hipLaunchKernelGGL(qproj_mfma, dim3((NROWS / 64) * 4), dim3(256), 0, stream,
                       q, w1T, b1, qp);
    hipLaunchKernelGGL(main_gemm, dim3((MM / 128) * 4), dim3(256), 0, stream,
                       v, w1T, qp, w2, logits4);
    hipLaunchKernelGGL(softmax_kernel, dim3((BB * SS * TT) / 4), dim3(256), 0, stream,
                       logits4, box_mask, starts, lengths, out);
}

// Round 9
// 233.178 us; speedup vs baseline: 1.0914x; 1.0116x over previous
//
#include <hip/hip_runtime.h>
#include <hip/hip_bf16.h>
#include <cstdint>
#include <cstddef>

#define BB 96
#define SS 4
#define TT 16
#define KK 36
#define VDIM 1024
#define QDIM 512
#define HH 512
#define W1R 1536
#define NROWS 3264
#define MM (NROWS * KK)   // 117504

typedef __attribute__((ext_vector_type(8))) short short8;
typedef __attribute__((ext_vector_type(4))) float f32x4;

static __device__ __forceinline__ unsigned short f2bf(float f) {
    union { float f; unsigned u; } v; v.f = f;
    unsigned u = v.u;
    u += 0x7FFFu + ((u >> 16) & 1u);   // RNE
    return (unsigned short)(u >> 16);
}

// packed fp32x2 -> bf16x2 via compiler intrinsic (emits v_cvt_pk_bf16_f32, RNE)
static __device__ __forceinline__ unsigned pk2(float lo, float hi) {
    __hip_bfloat162 h = __float22bfloat162_rn(make_float2(lo, hi));
    union { __hip_bfloat162 h; unsigned u; } cv;
    cv.h = h;
    return cv.u;
}

__device__ __forceinline__ void gload_lds16(const void* g, void* l) {
    __builtin_amdgcn_global_load_lds(
        (const __attribute__((address_space(1))) unsigned int*)g,
        (__attribute__((address_space(3))) unsigned int*)l, 16, 0, 0);
}

#define SB() __builtin_amdgcn_sched_barrier(0)

// ---------------------------------------------------------------------------
// Kernel 0: w1 (fp32 [1536][512]) -> w1T bf16 [512][1536]. grid (6, 512).
// ---------------------------------------------------------------------------
__global__ __launch_bounds__(256) void prep_w1T(const float* __restrict__ w1,
                                                unsigned short* __restrict__ w1T) {
    int k = blockIdx.x * 256 + threadIdx.x;   // 0..1535
    int c = blockIdx.y;                       // 0..511
    w1T[(size_t)c * W1R + k] = f2bf(w1[(size_t)k * HH + c]);
}

// ---------------------------------------------------------------------------
// Kernel 1: per-(b,s) segment starts/lengths via LDS scan (one block)
// ---------------------------------------------------------------------------
__global__ __launch_bounds__(512) void starts_kernel(const int* __restrict__ tags,
                                                     int* __restrict__ starts,
                                                     int* __restrict__ lengths) {
    __shared__ int sl[BB * SS];
    int tid = threadIdx.x;
    int len = 0;
    if (tid < BB * SS) {
#pragma unroll
        for (int i = 0; i < TT; ++i) len += tags[tid * TT + i];
        sl[tid] = len;
    }
    __syncthreads();
    for (int off = 1; off < BB * SS; off <<= 1) {
        int v = 0;
        if (tid < BB * SS && tid >= off) v = sl[tid - off];
        __syncthreads();
        if (tid < BB * SS) sl[tid] += v;
        __syncthreads();
    }
    if (tid < BB * SS) { starts[tid] = sl[tid] - len; lengths[tid] = len; }
}

// ---------------------------------------------------------------------------
// Kernel 2: qproj via MFMA. Tile 64(M) x 128(N), K=512 (8 steps of 64).
// grid 51*4. 256 thr = 4 waves (2x2), wave tile 32x64, acc[2][4].
// ---------------------------------------------------------------------------
__global__ __launch_bounds__(256, 3) void qproj_mfma(const float* __restrict__ q,
                                                     const unsigned short* __restrict__ w1T,
                                                     const float* __restrict__ b1,
                                                     float* __restrict__ qp) {
    __shared__ __align__(16) unsigned short At[2][64 * 64];    // 16 KB
    __shared__ __align__(16) unsigned short Bt[2][128 * 64];   // 32 KB

    int tid = threadIdx.x, lane = tid & 63, wid = tid >> 6;
    int wm = wid >> 1, wn = wid & 1;
    int bx = blockIdx.x;
    int nb = bx & 3, mb = bx >> 2;
    int n0q = mb * 64, cb = nb * 128;
    int lr = lane & 15, lg = lane >> 4;

    const float* a_base = q + (size_t)(n0q + wid * 16 + (lane >> 4)) * QDIM + (lane & 15) * 4;
    const unsigned short* b_base = w1T + (size_t)(cb + wid * 32 + (lane >> 3)) * W1R + 1024
                                 + (((lane & 7) ^ (lane >> 3)) * 8);

    f32x4 acc[2][4];
#pragma unroll
    for (int mt = 0; mt < 2; ++mt)
#pragma unroll
        for (int nt = 0; nt < 4; ++nt) acc[mt][nt] = (f32x4){0.f, 0.f, 0.f, 0.f};

#define QP_CVT_WRITE(DST, AR)                                                  \
    _Pragma("unroll") for (int p = 0; p < 4; ++p) {                            \
        int r = wid * 16 + (lane >> 4) + p * 4;                                \
        int boff = r * 128 + ((((lane & 15) * 8)) ^ ((r & 7) << 4));           \
        uint2 d;                                                               \
        d.x = pk2(AR[p].x, AR[p].y);                                           \
        d.y = pk2(AR[p].z, AR[p].w);                                           \
        *(uint2*)((char*)(DST) + boff) = d;                                    \
    }

#define QP_COMPUTE(AC, BC)                                                     \
    _Pragma("unroll") for (int kk = 0; kk < 2; ++kk) {                         \
        short8 af[2], bf[4];                                                   \
        _Pragma("unroll") for (int mt = 0; mt < 2; ++mt) {                     \
            int R = wm * 32 + mt * 16 + lr;                                    \
            int off = R * 128 + ((kk * 64 + lg * 16) ^ ((R & 7) << 4));        \
            af[mt] = *(const short8*)((const char*)(AC) + off);                \
        }                                                                      \
        _Pragma("unroll") for (int nt = 0; nt < 4; ++nt) {                     \
            int R = wn * 64 + nt * 16 + lr;                                    \
            int off = R * 128 + ((kk * 64 + lg * 16) ^ ((R & 7) << 4));        \
            bf[nt] = *(const short8*)((const char*)(BC) + off);                \
        }                                                                      \
        __builtin_amdgcn_s_setprio(1);                                         \
        _Pragma("unroll") for (int mt = 0; mt < 2; ++mt)                       \
            _Pragma("unroll") for (int nt = 0; nt < 4; ++nt)                   \
                acc[mt][nt] = __builtin_amdgcn_mfma_f32_16x16x32_bf16(         \
                    af[mt], bf[nt], acc[mt][nt], 0, 0, 0);                     \
        __builtin_amdgcn_s_setprio(0);                                         \
    }

    // prologue
    {
        float4 ar[4];
#pragma unroll
        for (int p = 0; p < 4; ++p) ar[p] = *(const float4*)(a_base + (size_t)p * 4 * QDIM);
#pragma unroll
        for (int o = 0; o < 4; ++o)
            gload_lds16(b_base + (size_t)o * 8 * W1R, &Bt[0][(wid * 32 + o * 8) * 64]);
        SB();
        QP_CVT_WRITE(&At[0][0], ar)
    }
#pragma unroll 1
    for (int t = 0; t < 7; ++t) {
        int k0 = (t + 1) * 64;
        const unsigned short* Ac = &At[t & 1][0];
        const unsigned short* Bc = &Bt[t & 1][0];
        unsigned short* An = &At[(t + 1) & 1][0];
        unsigned short* Bn = &Bt[(t + 1) & 1][0];
        float4 ar[4];
#pragma unroll
        for (int p = 0; p < 4; ++p)
            ar[p] = *(const float4*)(a_base + (size_t)p * 4 * QDIM + k0);
#pragma unroll
        for (int o = 0; o < 4; ++o)
            gload_lds16(b_base + (size_t)o * 8 * W1R + k0, &Bn[(wid * 32 + o * 8) * 64]);
        SB();
        asm volatile("s_waitcnt vmcnt(8)" ::: "memory");
        asm volatile("s_waitcnt lgkmcnt(0)" ::: "memory");
        __builtin_amdgcn_s_barrier();
        SB();
        QP_COMPUTE(Ac, Bc)
        SB();
        QP_CVT_WRITE(An, ar)
    }
    SB();
    asm volatile("s_waitcnt vmcnt(0)" ::: "memory");
    asm volatile("s_waitcnt lgkmcnt(0)" ::: "memory");
    __builtin_amdgcn_s_barrier();
    SB();
    QP_COMPUTE(&At[1][0], &Bt[1][0])
#undef QP_COMPUTE
#undef QP_CVT_WRITE

    // store qp + b1
#pragma unroll
    for (int nt = 0; nt < 4; ++nt) {
        int c = cb + wn * 64 + nt * 16 + lr;
        float b1v = b1[c];
#pragma unroll
        for (int mt = 0; mt < 2; ++mt)
#pragma unroll
            for (int r = 0; r < 4; ++r) {
                int row = wm * 32 + mt * 16 + lg * 4 + r;
                qp[(size_t)(n0q + row) * HH + c] = acc[mt][nt][r] + b1v;
            }
    }
}

// ---------------------------------------------------------------------------
// Kernel 3: main GEMM. Tile 128(M) x 128(N), BK=64, 16 K-steps.
// grid 3672 = 8 XCD-chunks of 459 (bijective).
// 256 thr = 4 waves (2x2), wave tile 64x64, acc[4][4].
// A: single-buffered LDS 16 KB, reg-staged with v_cvt_pk_bf16_f32 packing.
// B: double-buffered global_load_lds 2x16 KB, DMA issued AFTER barrier1
// (race-free), counted vmcnt(8) (never 0 in loop).
// LDS = 48 KB -> 3 blocks/CU.
// ---------------------------------------------------------------------------
__global__ __launch_bounds__(256, 3) void main_gemm(const float* __restrict__ v,
                                                    const unsigned short* __restrict__ w1T,
                                                    const float* __restrict__ qp,
                                                    const float* __restrict__ w2,
                                                    float* __restrict__ logits4) {
    __shared__ __align__(16) unsigned short At[128 * 64];      // 16 KB (single buf)
    __shared__ __align__(16) unsigned short Bt[2][128 * 64];   // 32 KB

    int tid = threadIdx.x, lane = tid & 63, wid = tid >> 6;
    int wm = wid >> 1, wn = wid & 1;
    int bx = blockIdx.x;
    int orig = (bx & 7) * 459 + (bx >> 3);      // bijective XCD chunking
    int nb = orig & 3, mb = orig >> 2;
    int m0 = mb * 128, cb = nb * 128;
    int lr = lane & 15, lg = lane >> 4;

    const float* a_base = v + (size_t)(m0 + wid * 32 + (lane >> 4)) * VDIM + (lane & 15) * 4;
    const unsigned short* b_base = w1T + (size_t)(cb + wid * 32 + (lane >> 3)) * W1R
                                 + (((lane & 7) ^ (lane >> 3)) * 8);

    f32x4 acc[4][4];
#pragma unroll
    for (int mt = 0; mt < 4; ++mt)
#pragma unroll
        for (int nt = 0; nt < 4; ++nt) acc[mt][nt] = (f32x4){0.f, 0.f, 0.f, 0.f};

#define MG_CVT_WRITE(AR)                                                       \
    _Pragma("unroll") for (int p = 0; p < 8; ++p) {                            \
        int r = wid * 32 + (lane >> 4) + p * 4;                                \
        int boff = r * 128 + ((((lane & 15) * 8)) ^ ((r & 7) << 4));           \
        uint2 d;                                                               \
        d.x = pk2(AR[p].x, AR[p].y);                                           \
        d.y = pk2(AR[p].z, AR[p].w);                                           \
        *(uint2*)((char*)&At[0] + boff) = d;                                   \
    }

#define MG_READ_A(AF, KKC)                                                     \
    _Pragma("unroll") for (int mt = 0; mt < 4; ++mt) {                         \
        int R = wm * 64 + mt * 16 + lr;                                        \
        int off = R * 128 + (((KKC) * 64 + lg * 16) ^ ((R & 7) << 4));         \
        AF[mt] = *(const short8*)((const char*)&At[0] + off);                  \
    }

#define MG_READ_B(BF, BC, KKC)                                                 \
    _Pragma("unroll") for (int nt = 0; nt < 4; ++nt) {                         \
        int R = wn * 64 + nt * 16 + lr;                                        \
        int off = R * 128 + (((KKC) * 64 + lg * 16) ^ ((R & 7) << 4));         \
        BF[nt] = *(const short8*)((const char*)(BC) + off);                    \
    }

#define MG_MFMA(AF, BF)                                                        \
    __builtin_amdgcn_s_setprio(1);                                             \
    _Pragma("unroll") for (int mt = 0; mt < 4; ++mt)                           \
        _Pragma("unroll") for (int nt = 0; nt < 4; ++nt)                       \
            acc[mt][nt] = __builtin_amdgcn_mfma_f32_16x16x32_bf16(             \
                AF[mt], BF[nt], acc[mt][nt], 0, 0, 0);                         \
    __builtin_amdgcn_s_setprio(0);

    // ---- prologue: B(0) DMA -> Bt[0]; A(0) -> regs -> cvt -> At ----
    {
#pragma unroll
        for (int o = 0; o < 4; ++o)
            gload_lds16(b_base + (size_t)o * 8 * W1R, &Bt[0][(wid * 32 + o * 8) * 64]);
        float4 ar[8];
#pragma unroll
        for (int p = 0; p < 8; ++p) ar[p] = *(const float4*)(a_base + (size_t)p * 4 * VDIM);
        SB();
        MG_CVT_WRITE(ar)
    }

#pragma unroll 1
    for (int t = 0; t < 16; ++t) {
        int kA = (t < 15) ? (t + 1) * 64 : 960;     // last iter: harmless dummy
        const unsigned short* Bc = &Bt[t & 1][0];
        unsigned short* Bn = &Bt[(t + 1) & 1][0];
        // issue A(t+1) -> regs  [8 vmem, newest]
        float4 ar[8];
#pragma unroll
        for (int p = 0; p < 8; ++p)
            ar[p] = *(const float4*)(a_base + (size_t)p * 4 * VDIM + kA);
        SB();
        asm volatile("s_waitcnt vmcnt(8)" ::: "memory");    // B(t) landed (8 newer A in flight)
        asm volatile("s_waitcnt lgkmcnt(0)" ::: "memory");  // my At writes done
        __builtin_amdgcn_s_barrier();                       // At(t)+B(t) visible; Bt[nxt] free
        SB();
        // issue B(t+1) DMA AFTER barrier1: race-free (all waves past their bf reads)
        if (t < 15) {
#pragma unroll
            for (int o = 0; o < 4; ++o)
                gload_lds16(b_base + (size_t)o * 8 * W1R + kA, Bn + (wid * 32 + o * 8) * 64);
        }
        SB();
        // kk0 reads+MFMA; kk1 reads free to overlap kk0 MFMA (no SB between)
        {
            short8 af0[4], bf0[4];
            MG_READ_A(af0, 0)
            MG_READ_B(bf0, Bc, 0)
            MG_MFMA(af0, bf0)
        }
        {
            short8 af1[4], bf1[4];
            MG_READ_A(af1, 1)
            MG_READ_B(bf1, Bc, 1)
            MG_MFMA(af1, bf1)
        }
        SB();
        asm volatile("s_waitcnt lgkmcnt(0)" ::: "memory");  // my At/Bt reads done
        __builtin_amdgcn_s_barrier();                       // all waves done reading At
        SB();
        if (t < 15) { MG_CVT_WRITE(ar) }                    // At <- A(t+1)
    }
#undef MG_MFMA
#undef MG_READ_A
#undef MG_READ_B
#undef MG_CVT_WRITE

    // ---- epilogue: relu(acc + qp) . w2 -> partial logits for cols [cb,cb+128)
    __syncthreads();   // drains dummy loads, frees At for reuse
    float* qs = (float*)&At[0];         // 5 x 128 slab of qp
    float* fl = qs + 5 * 128;           // 2 x 128 reduction scratch
    int n0 = m0 / KK;
    for (int i = tid; i < 5 * 128; i += 256) {
        int nn = n0 + (i >> 7);
        if (nn >= NROWS) nn = NROWS - 1;
        qs[i] = qp[(size_t)nn * HH + cb + (i & 127)];
    }
    __syncthreads();

    float part[4][4] = {{0.f}};
#pragma unroll
    for (int nt = 0; nt < 4; ++nt) {
        int c = wn * 64 + nt * 16 + lr;
        float w2v = w2[cb + c];
#pragma unroll
        for (int mt = 0; mt < 4; ++mt)
#pragma unroll
            for (int r = 0; r < 4; ++r) {
                int row = wm * 64 + mt * 16 + lg * 4 + r;
                int ni = (m0 + row) / KK - n0;
                float pre = acc[mt][nt][r] + qs[ni * 128 + c];
                part[mt][r] += fmaxf(pre, 0.f) * w2v;
            }
    }
#pragma unroll
    for (int mt = 0; mt < 4; ++mt)
#pragma unroll
        for (int r = 0; r < 4; ++r) {
            float s = part[mt][r];
            s += __shfl_xor(s, 1, 64);
            s += __shfl_xor(s, 2, 64);
            s += __shfl_xor(s, 4, 64);
            s += __shfl_xor(s, 8, 64);
            if (lr == 0) fl[wn * 128 + wm * 64 + mt * 16 + lg * 4 + r] = s;
        }
    __syncthreads();
    if (tid < 128)
        logits4[(size_t)nb * MM + m0 + tid] = fl[tid] + fl[128 + tid];
}

// ---------------------------------------------------------------------------
// Kernel 4: masked softmax. One wave per (b,s,t); sums 4 logit partials.
// ---------------------------------------------------------------------------
__global__ __launch_bounds__(256) void softmax_kernel(const float* __restrict__ logits4,
                                                      const float* __restrict__ box_mask,
                                                      const int* __restrict__ starts,
                                                      const int* __restrict__ lengths,
                                                      float* __restrict__ out) {
    int lane = threadIdx.x & 63;
    int g = blockIdx.x * 4 + (threadIdx.x >> 6);   // 0 .. B*S*T-1
    int t   = g & (TT - 1);
    int row = g >> 4;
    int b   = row >> 2;

    int length = lengths[row];
    int start  = starts[row];

    int k = lane;
    bool kv = k < KK;
    float mval = kv ? box_mask[b * KK + k] : 0.f;
    bool act = kv && (mval != 0.f);

    float l = 0.f;
    if (act && t < length) {
        size_t idx = (size_t)(start + t) * KK + k;
        l = logits4[idx] + logits4[MM + idx] + logits4[2 * (size_t)MM + idx]
          + logits4[3 * (size_t)MM + idx];
    }

    float lm = act ? l : -1e30f;
#pragma unroll
    for (int off = 32; off >= 1; off >>= 1) lm = fmaxf(lm, __shfl_xor(lm, off, 64));

    float e = act ? expf(l - lm) : 0.f;
    float se = e;
#pragma unroll
    for (int off = 32; off >= 1; off >>= 1) se += __shfl_xor(se, off, 64);

    if (kv) out[(size_t)g * KK + k] = e / se;
}

// ---------------------------------------------------------------------------
extern "C" void kernel_launch(void* const* d_in, const int* in_sizes, int n_in,
                              void* d_out, int out_size, void* d_ws, size_t ws_size,
                              hipStream_t stream) {
    const float* v        = (const float*)d_in[0];
    const float* q        = (const float*)d_in[1];
    const float* box_mask = (const float*)d_in[2];
    const int*   tags     = (const int*)d_in[3];
    const float* w1       = (const float*)d_in[4];
    const float* b1       = (const float*)d_in[5];
    const float* w2       = (const float*)d_in[6];

    char* ws = (char*)d_ws;
    unsigned short* w1T   = (unsigned short*)ws;                 // 1,572,864 B
    float* qp      = (float*)(ws + 1572864);                     // 6,684,672 B
    float* logits4 = (float*)(ws + 1572864 + 6684672);           // 1,880,064 B
    int*   starts  = (int*)(ws + 1572864 + 6684672 + 1880064);
    int*   lengths = (int*)(ws + 1572864 + 6684672 + 1880064 + 1536);
    float* out     = (float*)d_out;

    hipLaunchKernelGGL(prep_w1T, dim3(6, 512), dim3(256), 0, stream, w1, w1T);
    hipLaunchKernelGGL(starts_kernel, dim3(1), dim3(512), 0, stream, tags, starts, lengths);
    hipLaunchKernelGGL(qproj_mfma, dim3((NROWS / 64) * 4), dim3(256), 0, stream,
                       q, w1T, b1, qp);
    hipLaunchKernelGGL(main_gemm, dim3((MM / 128) * 4), dim3(256), 0, stream,
                       v, w1T, qp, w2, logits4);
    hipLaunchKernelGGL(softmax_kernel, dim3((BB * SS * TT) / 4), dim3(256), 0, stream,
                       logits4, box_mask, starts, lengths, out);
}